// Round 1
// baseline (689.557 us; speedup 1.0000x reference)
//
#include <hip/hip_runtime.h>
#include <cstdint>
#include <cstddef>

// Problem constants (fixed by setup_inputs)
#define NB 8
#define LQ 5440
#define DM 256
#define MROWS (NB * LQ)   // 43520

// ---------------------------------------------------------------------------
// Tiled fp32 GEMM:  C[M x N] = A[M x 256] @ B[256 x N] + bias[N]
// Block tile 64x64, K-tile 32, 256 threads, 4x4 micro-tile per thread.
// M (=43520) % 64 == 0, N % 64 == 0, K == 256 — no bounds checks needed.
// ---------------------------------------------------------------------------
__global__ __launch_bounds__(256) void gemm_bias(
    const float* __restrict__ A, const float* __restrict__ B,
    const float* __restrict__ bias, float* __restrict__ C, int N)
{
    constexpr int K = 256;
    constexpr int BK = 32;
    __shared__ float As[BK][64 + 4];   // stored transposed: As[k][m]
    __shared__ float Bs[BK][64 + 4];   // Bs[k][n]; pad 4 keeps 16B alignment

    const int bm = blockIdx.y * 64;
    const int bn = blockIdx.x * 64;
    const int t  = threadIdx.x;
    const int tx = t & 15;   // output col group
    const int ty = t >> 4;   // output row group

    float acc[4][4] = {{0.f}};

    for (int k0 = 0; k0 < K; k0 += BK) {
        // Stage A tile (64x32) and B tile (32x64), 2 float4 each per thread.
#pragma unroll
        for (int i = 0; i < 2; ++i) {
            const int f = t * 2 + i;           // 0..511
            // A: row-major [64][32] -> transposed into As[k][m]
            const int m  = f >> 3;
            const int kc = (f & 7) << 2;
            const float4 av = *reinterpret_cast<const float4*>(
                &A[(size_t)(bm + m) * K + k0 + kc]);
            As[kc + 0][m] = av.x;
            As[kc + 1][m] = av.y;
            As[kc + 2][m] = av.z;
            As[kc + 3][m] = av.w;
            // B: row-major [32][64]
            const int kk = f >> 4;
            const int nc = (f & 15) << 2;
            *reinterpret_cast<float4*>(&Bs[kk][nc]) =
                *reinterpret_cast<const float4*>(&B[(size_t)(k0 + kk) * N + bn + nc]);
        }
        __syncthreads();

#pragma unroll
        for (int kk = 0; kk < BK; ++kk) {
            float4 a4 = *reinterpret_cast<const float4*>(&As[kk][ty * 4]);
            float4 b4 = *reinterpret_cast<const float4*>(&Bs[kk][tx * 4]);
            const float* a = reinterpret_cast<const float*>(&a4);
            const float* b = reinterpret_cast<const float*>(&b4);
#pragma unroll
            for (int i = 0; i < 4; ++i)
#pragma unroll
                for (int j = 0; j < 4; ++j)
                    acc[i][j] = fmaf(a[i], b[j], acc[i][j]);
        }
        __syncthreads();
    }

#pragma unroll
    for (int i = 0; i < 4; ++i) {
        const int m = bm + ty * 4 + i;
        float4 o;
        o.x = acc[i][0] + bias[bn + tx * 4 + 0];
        o.y = acc[i][1] + bias[bn + tx * 4 + 1];
        o.z = acc[i][2] + bias[bn + tx * 4 + 2];
        o.w = acc[i][3] + bias[bn + tx * 4 + 3];
        *reinterpret_cast<float4*>(&C[(size_t)m * N + bn + tx * 4]) = o;
    }
}

// ---------------------------------------------------------------------------
// Fused sampling kernel: per (n,q) row — softmax over 16 logits per head,
// location computation, bilinear gather from v, weighted accumulate.
// thread t = channel (h = t/32, c = t%32)  ->  gathers coalesce 128B per head.
// pre may alias offlog (row is fully read into LDS before being written).
// ---------------------------------------------------------------------------
__global__ __launch_bounds__(256) void sample_kernel(
    const float* __restrict__ v,        // [NB][LQ][256]
    const float* __restrict__ offlog,   // [NB][LQ][256]
    const float* __restrict__ attnlog,  // [NB][LQ][128]
    const float* __restrict__ refpts,   // [NB][LQ][4][2]
    float* __restrict__ pre)            // [NB][LQ][256]
{
    const int row = blockIdx.x;          // n*LQ + q
    const int n   = row / LQ;
    const int t   = threadIdx.x;

    __shared__ float soff[256];
    __shared__ float slog[128];
    __shared__ float slocx[128], slocy[128], sw[128];
    __shared__ float smax[8], ssum[8];

    soff[t] = offlog[(size_t)row * 256 + t];
    if (t < 128) slog[t] = attnlog[(size_t)row * 128 + t];
    __syncthreads();

    if (t < 8) {
        float m = -1e30f;
        for (int i = 0; i < 16; ++i) m = fmaxf(m, slog[t * 16 + i]);
        float s = 0.f;
        for (int i = 0; i < 16; ++i) s += __expf(slog[t * 16 + i] - m);
        smax[t] = m;
        ssum[t] = s;
    }
    __syncthreads();

    if (t < 128) {
        const int h  = t >> 4;
        const int lp = t & 15;
        const int l  = lp >> 2;
        const float scale = (float)(64 >> l);     // W == H per level
        const float rx = refpts[(size_t)row * 8 + l * 2 + 0];
        const float ry = refpts[(size_t)row * 8 + l * 2 + 1];
        slocx[t] = rx + soff[h * 32 + lp * 2 + 0] / scale;
        slocy[t] = ry + soff[h * 32 + lp * 2 + 1] / scale;
        sw[t]    = __expf(slog[t] - smax[h]) / ssum[h];
    }
    __syncthreads();

    const int h = t >> 5;
    const float* vn = v + (size_t)n * LQ * 256;
    float acc = 0.f;

#pragma unroll
    for (int l = 0; l < 4; ++l) {
        const int W = 64 >> l;
        const int start = (l == 0) ? 0 : (l == 1) ? 4096 : (l == 2) ? 5120 : 5376;
#pragma unroll
        for (int p = 0; p < 4; ++p) {
            const int s = h * 16 + l * 4 + p;
            const float x = slocx[s] * (float)W - 0.5f;
            const float y = slocy[s] * (float)W - 0.5f;
            const float fx = floorf(x), fy = floorf(y);
            const float wx = x - fx, wy = y - fy;
            const int xi = (int)fx, yi = (int)fy;
            const float wgt = sw[s];
            float vs = 0.f;
#pragma unroll
            for (int dy = 0; dy < 2; ++dy) {
                const int yy = yi + dy;
                if (yy < 0 || yy >= W) continue;
                const float wyv = dy ? wy : 1.f - wy;
#pragma unroll
                for (int dx = 0; dx < 2; ++dx) {
                    const int xx = xi + dx;
                    if (xx < 0 || xx >= W) continue;
                    const float wxv = dx ? wx : 1.f - wx;
                    vs = fmaf(vn[(size_t)(start + yy * W + xx) * 256 + t] * wxv, wyv, vs);
                }
            }
            acc = fmaf(wgt, vs, acc);
        }
    }

    pre[(size_t)row * 256 + t] = acc;
}

// ---------------------------------------------------------------------------
extern "C" void kernel_launch(void* const* d_in, const int* in_sizes, int n_in,
                              void* d_out, int out_size, void* d_ws, size_t ws_size,
                              hipStream_t stream)
{
    const float* query   = (const float*)d_in[0];
    const float* refpts  = (const float*)d_in[1];
    // d_in[2] spatial_shapes, d_in[3] level_start_index: fixed, hard-coded
    const float* W_value = (const float*)d_in[4];
    const float* b_value = (const float*)d_in[5];
    const float* W_off   = (const float*)d_in[6];
    const float* b_off   = (const float*)d_in[7];
    const float* W_attn  = (const float*)d_in[8];
    const float* b_attn  = (const float*)d_in[9];
    const float* W_out   = (const float*)d_in[10];
    const float* b_out   = (const float*)d_in[11];
    float* out = (float*)d_out;

    // Workspace layout (fp32): v | offlog(->pre, aliased) | attnlog
    float* ws_v    = (float*)d_ws;
    float* ws_off  = ws_v   + (size_t)MROWS * 256;
    float* ws_attn = ws_off + (size_t)MROWS * 256;
    // requires ws_size >= 43520*(256+256+128)*4 = ~106.3 MiB

    const dim3 g256(4, MROWS / 64);
    const dim3 g128(2, MROWS / 64);

    // v = query @ W_value + b_value
    gemm_bias<<<g256, 256, 0, stream>>>(query, W_value, b_value, ws_v, 256);
    // off logits = v @ W_off + b_off
    gemm_bias<<<g256, 256, 0, stream>>>(ws_v, W_off, b_off, ws_off, 256);
    // attn logits = v @ W_attn + b_attn
    gemm_bias<<<g128, 256, 0, stream>>>(ws_v, W_attn, b_attn, ws_attn, 128);
    // fused softmax + bilinear sampling -> pre (overwrites offlog in place)
    sample_kernel<<<dim3(MROWS), 256, 0, stream>>>(ws_v, ws_off, ws_attn, refpts, ws_off);
    // out = pre @ W_out + b_out
    gemm_bias<<<g256, 256, 0, stream>>>(ws_off, W_out, b_out, out, 256);
}

// Round 2
// 408.810 us; speedup vs baseline: 1.6867x; 1.6867x over previous
//
#include <hip/hip_runtime.h>
#include <cstdint>
#include <cstddef>

// Problem constants (fixed by setup_inputs)
#define NB 8
#define LQ 5440
#define DM 256
#define MROWS (NB * LQ)   // 43520

// ---------------------------------------------------------------------------
// Tiled fp32 GEMM:  C[M x N] = A[M x 256] @ B[256 x N] + bias[N]
// Block tile 64x64, K-tile 32, 256 threads, 4x4 micro-tile per thread.
// ---------------------------------------------------------------------------
__global__ __launch_bounds__(256) void gemm_bias(
    const float* __restrict__ A, const float* __restrict__ B,
    const float* __restrict__ bias, float* __restrict__ C, int N)
{
    constexpr int K = 256;
    constexpr int BK = 32;
    __shared__ float As[BK][64 + 4];   // stored transposed: As[k][m]
    __shared__ float Bs[BK][64 + 4];   // Bs[k][n]

    const int bm = blockIdx.y * 64;
    const int bn = blockIdx.x * 64;
    const int t  = threadIdx.x;
    const int tx = t & 15;
    const int ty = t >> 4;

    float acc[4][4] = {{0.f}};

    for (int k0 = 0; k0 < K; k0 += BK) {
#pragma unroll
        for (int i = 0; i < 2; ++i) {
            const int f = t * 2 + i;           // 0..511
            const int m  = f >> 3;
            const int kc = (f & 7) << 2;
            const float4 av = *reinterpret_cast<const float4*>(
                &A[(size_t)(bm + m) * K + k0 + kc]);
            As[kc + 0][m] = av.x;
            As[kc + 1][m] = av.y;
            As[kc + 2][m] = av.z;
            As[kc + 3][m] = av.w;
            const int kk = f >> 4;
            const int nc = (f & 15) << 2;
            *reinterpret_cast<float4*>(&Bs[kk][nc]) =
                *reinterpret_cast<const float4*>(&B[(size_t)(k0 + kk) * N + bn + nc]);
        }
        __syncthreads();

#pragma unroll
        for (int kk = 0; kk < BK; ++kk) {
            float4 a4 = *reinterpret_cast<const float4*>(&As[kk][ty * 4]);
            float4 b4 = *reinterpret_cast<const float4*>(&Bs[kk][tx * 4]);
            const float* a = reinterpret_cast<const float*>(&a4);
            const float* b = reinterpret_cast<const float*>(&b4);
#pragma unroll
            for (int i = 0; i < 4; ++i)
#pragma unroll
                for (int j = 0; j < 4; ++j)
                    acc[i][j] = fmaf(a[i], b[j], acc[i][j]);
        }
        __syncthreads();
    }

#pragma unroll
    for (int i = 0; i < 4; ++i) {
        const int m = bm + ty * 4 + i;
        float4 o;
        o.x = acc[i][0] + bias[bn + tx * 4 + 0];
        o.y = acc[i][1] + bias[bn + tx * 4 + 1];
        o.z = acc[i][2] + bias[bn + tx * 4 + 2];
        o.w = acc[i][3] + bias[bn + tx * 4 + 3];
        *reinterpret_cast<float4*>(&C[(size_t)m * N + bn + tx * 4]) = o;
    }
}

// ---------------------------------------------------------------------------
// Fused sampling kernel, wave-per-row version.
//   block = 256 threads = 4 waves; wave w handles row = blockIdx.x*4 + w.
//   lane = 4 channels (float4 gathers); head h = lane>>3 (8 lanes/head).
//   Softmax over 16 logits/head via 8-lane __shfl_xor reduction (in-register).
//   Per-sample (locx,locy,w) broadcast via padded LDS float4 (stride 17 ->
//   conflict-free: bank = (4h + 4j) % 32 distinct across the 8 head-groups).
//   OOB handled branchlessly: clamp index, zero the bilinear weight.
//   pre may alias offlog: each row is fully read by its wave before the
//   wave's final store to the same row.
// ---------------------------------------------------------------------------
__global__ __launch_bounds__(256) void sample_kernel(
    const float* __restrict__ v,        // [NB][LQ][256]
    const float* __restrict__ offlog,   // [NB][LQ][256]
    const float* __restrict__ attnlog,  // [NB][LQ][128]
    const float* __restrict__ refpts,   // [NB][LQ][4][2]
    float* __restrict__ pre)            // [NB][LQ][256]
{
    const int lane = threadIdx.x & 63;
    const int wv   = threadIdx.x >> 6;
    const int row  = blockIdx.x * 4 + wv;
    const int n    = row / LQ;

    __shared__ float4 slw[4][136];      // [wave][h*17 + j], padded

    // ---- load this row's offsets + attention logits (vectorized) ----
    const float4 off4 = reinterpret_cast<const float4*>(offlog)[(size_t)row * 64 + lane];
    const float2 lg2  = reinterpret_cast<const float2*>(attnlog)[(size_t)row * 64 + lane];

    const int h   = lane >> 3;          // head 0..7
    const int k   = lane & 7;           // position within head group
    const int lev = k >> 1;             // level of this lane's two samples
    const float rx = refpts[(size_t)row * 8 + lev * 2 + 0];
    const float ry = refpts[(size_t)row * 8 + lev * 2 + 1];

    // ---- softmax over the head's 16 logits (8 lanes x 2 each) ----
    float m = fmaxf(lg2.x, lg2.y);
    m = fmaxf(m, __shfl_xor(m, 1));
    m = fmaxf(m, __shfl_xor(m, 2));
    m = fmaxf(m, __shfl_xor(m, 4));
    const float e0 = __expf(lg2.x - m);
    const float e1 = __expf(lg2.y - m);
    float s = e0 + e1;
    s += __shfl_xor(s, 1);
    s += __shfl_xor(s, 2);
    s += __shfl_xor(s, 4);
    const float inv = 1.f / s;

    // ---- locations for this lane's two samples (j0 = 2k, j0+1) ----
    const float rs = 0.015625f * (float)(1 << lev);   // 1/(64>>lev)
    const int j0 = 2 * k;
    slw[wv][h * 17 + j0]     = make_float4(rx + off4.x * rs, ry + off4.y * rs, e0 * inv, 0.f);
    slw[wv][h * 17 + j0 + 1] = make_float4(rx + off4.z * rs, ry + off4.w * rs, e1 * inv, 0.f);
    __syncthreads();

    // ---- gather + weighted accumulate; lane covers channels 4*lane.. ----
    const float4* vn = reinterpret_cast<const float4*>(v) + (size_t)n * (LQ * 64) + lane;
    float4 acc = make_float4(0.f, 0.f, 0.f, 0.f);

#pragma unroll
    for (int j = 0; j < 16; ++j) {
        const int lv = j >> 2;
        const int W  = 64 >> lv;
        const int start = (lv == 0) ? 0 : (lv == 1) ? 4096 : (lv == 2) ? 5120 : 5376;
        const float4 lw = slw[wv][h * 17 + j];

        const float x = lw.x * (float)W - 0.5f;
        const float y = lw.y * (float)W - 0.5f;
        const float fx = floorf(x), fy = floorf(y);
        const int xi = (int)fx, yi = (int)fy;
        const float wx = x - fx, wy = y - fy;

        const int x0 = min(max(xi, 0), W - 1);
        const int x1 = min(max(xi + 1, 0), W - 1);
        const int y0 = min(max(yi, 0), W - 1);
        const int y1 = min(max(yi + 1, 0), W - 1);
        const float vx0 = (xi >= 0 && xi < W)          ? (1.f - wx) : 0.f;
        const float vx1 = (xi + 1 >= 0 && xi + 1 < W)  ? wx          : 0.f;
        const float vy0 = (yi >= 0 && yi < W)          ? (1.f - wy) : 0.f;
        const float vy1 = (yi + 1 >= 0 && yi + 1 < W)  ? wy          : 0.f;

        const float4 p00 = vn[(size_t)(start + y0 * W + x0) * 64];
        const float4 p01 = vn[(size_t)(start + y0 * W + x1) * 64];
        const float4 p10 = vn[(size_t)(start + y1 * W + x0) * 64];
        const float4 p11 = vn[(size_t)(start + y1 * W + x1) * 64];

        const float w00 = lw.z * vy0 * vx0;
        const float w01 = lw.z * vy0 * vx1;
        const float w10 = lw.z * vy1 * vx0;
        const float w11 = lw.z * vy1 * vx1;

        acc.x += w00 * p00.x + w01 * p01.x + w10 * p10.x + w11 * p11.x;
        acc.y += w00 * p00.y + w01 * p01.y + w10 * p10.y + w11 * p11.y;
        acc.z += w00 * p00.z + w01 * p01.z + w10 * p10.z + w11 * p11.z;
        acc.w += w00 * p00.w + w01 * p01.w + w10 * p10.w + w11 * p11.w;
    }

    reinterpret_cast<float4*>(pre)[(size_t)row * 64 + lane] = acc;
}

// ---------------------------------------------------------------------------
extern "C" void kernel_launch(void* const* d_in, const int* in_sizes, int n_in,
                              void* d_out, int out_size, void* d_ws, size_t ws_size,
                              hipStream_t stream)
{
    const float* query   = (const float*)d_in[0];
    const float* refpts  = (const float*)d_in[1];
    const float* W_value = (const float*)d_in[4];
    const float* b_value = (const float*)d_in[5];
    const float* W_off   = (const float*)d_in[6];
    const float* b_off   = (const float*)d_in[7];
    const float* W_attn  = (const float*)d_in[8];
    const float* b_attn  = (const float*)d_in[9];
    const float* W_out   = (const float*)d_in[10];
    const float* b_out   = (const float*)d_in[11];
    float* out = (float*)d_out;

    // Workspace layout (fp32): v | offlog(->pre, aliased) | attnlog
    float* ws_v    = (float*)d_ws;
    float* ws_off  = ws_v   + (size_t)MROWS * 256;
    float* ws_attn = ws_off + (size_t)MROWS * 256;

    const dim3 g256(4, MROWS / 64);
    const dim3 g128(2, MROWS / 64);

    gemm_bias<<<g256, 256, 0, stream>>>(query, W_value, b_value, ws_v, 256);
    gemm_bias<<<g256, 256, 0, stream>>>(ws_v, W_off, b_off, ws_off, 256);
    gemm_bias<<<g128, 256, 0, stream>>>(ws_v, W_attn, b_attn, ws_attn, 128);
    sample_kernel<<<dim3(MROWS / 4), 256, 0, stream>>>(ws_v, ws_off, ws_attn, refpts, ws_off);
    gemm_bias<<<g256, 256, 0, stream>>>(ws_off, W_out, b_out, out, 256);
}

// Round 4
// 160.015 us; speedup vs baseline: 4.3093x; 2.5548x over previous
//
#include <hip/hip_runtime.h>
#include <hip/hip_bf16.h>
#include <cstdint>
#include <cstddef>

// Problem constants (fixed by setup_inputs)
#define NB 8
#define LQ 5440
#define MROWS (NB * LQ)   // 43520

typedef __attribute__((ext_vector_type(8))) short          bf16x8;
typedef __attribute__((ext_vector_type(4))) float          f32x4;
typedef __attribute__((ext_vector_type(8))) unsigned short ushort8_t;

__device__ __forceinline__ float b2f(unsigned short u) {
    return __uint_as_float(((unsigned int)u) << 16);
}
__device__ __forceinline__ unsigned short f2b(float f) {
    __hip_bfloat16 h = __float2bfloat16(f);   // RNE
    return *reinterpret_cast<unsigned short*>(&h);
}

// ---------------------------------------------------------------------------
// Prep: convert + transpose the 4 weight matrices to bf16 [N][K] layout.
//   WvT [256][256], WoaT [384][256] (off cols 0..255, attn cols 256..383),
//   WoT [256][256].  229376 elements total -> 896 blocks x 256.
// ---------------------------------------------------------------------------
__global__ __launch_bounds__(256) void prep_weights(
    const float* __restrict__ Wv, const float* __restrict__ Woff,
    const float* __restrict__ Wat, const float* __restrict__ Wo,
    unsigned short* __restrict__ WvT, unsigned short* __restrict__ WoaT,
    unsigned short* __restrict__ WoT)
{
    const int id = blockIdx.x * 256 + threadIdx.x;
    if (id < 65536) {
        const int n = id >> 8, k = id & 255;
        WvT[id] = f2b(Wv[k * 256 + n]);
    } else if (id < 65536 + 98304) {
        const int p = id - 65536;
        const int n = p >> 8, k = p & 255;
        WoaT[p] = (n < 256) ? f2b(Woff[k * 256 + n])
                            : f2b(Wat[k * 128 + (n - 256)]);
    } else {
        const int p = id - (65536 + 98304);
        const int n = p >> 8, k = p & 255;
        WoT[p] = f2b(Wo[k * 256 + n]);
    }
}

// ---------------------------------------------------------------------------
// bf16 MFMA GEMM: C[M x N] = A[M x 256] @ Bt^T + bias
//   A: [M][256] fp32 (A_FP32) or bf16;  Bt: [N][256] bf16 (pre-transposed).
//   Tile 128x128, BK=32, 256 threads = 4 waves (2x2 of 64x64).
//   mfma_f32_16x16x32_bf16; A frag: lane -> row (l&15), k (l>>4)*8..+7;
//   B frag: lane -> col (l&15), same k;  C/D: col=l&15, row=(l>>4)*4+reg.
//   LDS rows padded to 40 bf16 (80B).
//   BF16_OUT: pack col-pairs via __shfl_xor(1), even lanes store bfloat162.
//   Column split >= `split` goes to C1 (gemm23 writes off16 + attn16).
// ---------------------------------------------------------------------------
#define LDT 40

template<bool A_FP32, bool BF16_OUT>
__global__ __launch_bounds__(256) void gemm_mfma(
    const void* __restrict__ Ap, const unsigned short* __restrict__ Bt,
    const float* __restrict__ bias0, const float* __restrict__ bias1,
    void* __restrict__ C0, void* __restrict__ C1,
    int cs0, int cs1, int split)
{
    __shared__ unsigned short As[128 * LDT];
    __shared__ unsigned short Bs[128 * LDT];

    const int bm = blockIdx.y * 128;
    const int bn = blockIdx.x * 128;
    const int t    = threadIdx.x;
    const int lane = t & 63;
    const int wid  = t >> 6;
    const int wm   = (wid >> 1) * 64;
    const int wn   = (wid & 1) * 64;
    const int c    = lane & 15;
    const int qq   = lane >> 4;

    const int tr = t >> 1;            // staging row 0..127
    const int kh = (t & 1) * 16;      // staging k-half 0/16

    f32x4 acc[4][4];
#pragma unroll
    for (int i = 0; i < 4; ++i)
#pragma unroll
        for (int j = 0; j < 4; ++j)
            acc[i][j] = (f32x4){0.f, 0.f, 0.f, 0.f};

    for (int k0 = 0; k0 < 256; k0 += 32) {
        // ---- stage A (convert fp32->bf16 if needed) ----
        if (A_FP32) {
            const float4* Af = reinterpret_cast<const float4*>(
                (const float*)Ap + (size_t)(bm + tr) * 256 + k0 + kh);
            const float4 a0 = Af[0], a1 = Af[1], a2 = Af[2], a3 = Af[3];
            ushort8_t u0, u1;
            u0[0]=f2b(a0.x); u0[1]=f2b(a0.y); u0[2]=f2b(a0.z); u0[3]=f2b(a0.w);
            u0[4]=f2b(a1.x); u0[5]=f2b(a1.y); u0[6]=f2b(a1.z); u0[7]=f2b(a1.w);
            u1[0]=f2b(a2.x); u1[1]=f2b(a2.y); u1[2]=f2b(a2.z); u1[3]=f2b(a2.w);
            u1[4]=f2b(a3.x); u1[5]=f2b(a3.y); u1[6]=f2b(a3.z); u1[7]=f2b(a3.w);
            *reinterpret_cast<ushort8_t*>(&As[tr * LDT + kh])     = u0;
            *reinterpret_cast<ushort8_t*>(&As[tr * LDT + kh + 8]) = u1;
        } else {
            const ushort8_t* Ab = reinterpret_cast<const ushort8_t*>(
                (const unsigned short*)Ap + (size_t)(bm + tr) * 256 + k0 + kh);
            *reinterpret_cast<ushort8_t*>(&As[tr * LDT + kh])     = Ab[0];
            *reinterpret_cast<ushort8_t*>(&As[tr * LDT + kh + 8]) = Ab[1];
        }
        // ---- stage B ----
        {
            const ushort8_t* Bb = reinterpret_cast<const ushort8_t*>(
                Bt + (size_t)(bn + tr) * 256 + k0 + kh);
            *reinterpret_cast<ushort8_t*>(&Bs[tr * LDT + kh])     = Bb[0];
            *reinterpret_cast<ushort8_t*>(&Bs[tr * LDT + kh + 8]) = Bb[1];
        }
        __syncthreads();

        bf16x8 af[4], bfr[4];
#pragma unroll
        for (int i = 0; i < 4; ++i)
            af[i] = *reinterpret_cast<const bf16x8*>(
                &As[(wm + i * 16 + c) * LDT + qq * 8]);
#pragma unroll
        for (int j = 0; j < 4; ++j)
            bfr[j] = *reinterpret_cast<const bf16x8*>(
                &Bs[(wn + j * 16 + c) * LDT + qq * 8]);
#pragma unroll
        for (int i = 0; i < 4; ++i)
#pragma unroll
            for (int j = 0; j < 4; ++j)
                acc[i][j] = __builtin_amdgcn_mfma_f32_16x16x32_bf16(
                    af[i], bfr[j], acc[i][j], 0, 0, 0);
        __syncthreads();
    }

    // ---- epilogue ----
#pragma unroll
    for (int j = 0; j < 4; ++j) {
        const int col    = bn + wn + j * 16 + c;
        const bool second = col >= split;
        const int ccol   = second ? col - split : col;
        const float bv   = second ? bias1[ccol] : bias0[ccol];
#pragma unroll
        for (int i = 0; i < 4; ++i) {
#pragma unroll
            for (int r = 0; r < 4; ++r) {
                const int row = bm + wm + i * 16 + qq * 4 + r;
                const float v0 = acc[i][j][r] + bv;
                if (BF16_OUT) {
                    const float v1 = __shfl_xor(v0, 1);
                    if ((lane & 1) == 0) {
                        __hip_bfloat162 h2;
                        h2.x = __float2bfloat16(v0);
                        h2.y = __float2bfloat16(v1);
                        unsigned short* Cb = (unsigned short*)(second ? C1 : C0);
                        const int cs = second ? cs1 : cs0;
                        *reinterpret_cast<__hip_bfloat162*>(
                            Cb + (size_t)row * cs + ccol) = h2;
                    }
                } else {
                    float* Cf = (float*)C0;
                    Cf[(size_t)row * cs0 + col] = v0;
                }
            }
        }
    }
}

// ---------------------------------------------------------------------------
// Fused sampling, bf16 in/out, precomputed weights+addresses.
//   4 waves/block, wave = one row. Lane (h = lane>>3, k = lane&7) owns
//   channels h*32 + 4k .. +3  (ushort4 index == lane).
//   Precompute: lane computes its 2 (head,sample) pairs -> 4 corner weights
//   (incl. softmax) + 4 byte offsets into v16 -> padded LDS (stride 17/head).
//   Main loop: per sample j: 2 LDS b128 broadcasts + 4 x ushort4 gathers.
// ---------------------------------------------------------------------------
__global__ __launch_bounds__(256) void sample_kernel(
    const unsigned short* __restrict__ v16,     // [NB][LQ][256]
    const unsigned short* __restrict__ off16,   // [NB][LQ][256]
    const unsigned short* __restrict__ attn16,  // [NB][LQ][128]
    const float* __restrict__ refpts,           // [NB][LQ][4][2] fp32
    unsigned short* __restrict__ pre16)         // [NB][LQ][256]
{
    const int lane = threadIdx.x & 63;
    const int wv   = threadIdx.x >> 6;
    const int row  = blockIdx.x * 4 + wv;
    const int n    = row / LQ;

    __shared__ float4 sW[4][136];
    __shared__ int4   sI[4][136];

    const ushort4 o4 = reinterpret_cast<const ushort4*>(off16)[(size_t)row * 64 + lane];
    const unsigned int lg = reinterpret_cast<const unsigned int*>(attn16)[(size_t)row * 64 + lane];
    const float l0 = b2f((unsigned short)(lg & 0xffff));
    const float l1 = b2f((unsigned short)(lg >> 16));

    const int h   = lane >> 3;
    const int k   = lane & 7;
    const int j0  = 2 * k;
    const int lev = j0 >> 2;
    const float rx = refpts[(size_t)row * 8 + lev * 2 + 0];
    const float ry = refpts[(size_t)row * 8 + lev * 2 + 1];

    // softmax across the head's 16 logits (8 lanes x 2)
    float m = fmaxf(l0, l1);
    m = fmaxf(m, __shfl_xor(m, 1));
    m = fmaxf(m, __shfl_xor(m, 2));
    m = fmaxf(m, __shfl_xor(m, 4));
    const float e0 = __expf(l0 - m);
    const float e1 = __expf(l1 - m);
    float s = e0 + e1;
    s += __shfl_xor(s, 1);
    s += __shfl_xor(s, 2);
    s += __shfl_xor(s, 4);
    const float inv = 1.f / s;

    const int  W     = 64 >> lev;
    const int  start = (lev == 0) ? 0 : (lev == 1) ? 4096 : (lev == 2) ? 5120 : 5376;
    const float rs   = 0.015625f * (float)(1 << lev);

#pragma unroll
    for (int pp = 0; pp < 2; ++pp) {
        const float lx = rx + b2f(pp ? o4.z : o4.x) * rs;
        const float ly = ry + b2f(pp ? o4.w : o4.y) * rs;
        const float wgt = (pp ? e1 : e0) * inv;

        const float x = lx * (float)W - 0.5f;
        const float y = ly * (float)W - 0.5f;
        const float fx = floorf(x), fy = floorf(y);
        const int xi = (int)fx, yi = (int)fy;
        const float wx = x - fx, wy = y - fy;

        const int x0 = min(max(xi, 0), W - 1);
        const int x1 = min(max(xi + 1, 0), W - 1);
        const int y0 = min(max(yi, 0), W - 1);
        const int y1 = min(max(yi + 1, 0), W - 1);
        const float vx0 = (xi >= 0 && xi < W)         ? (1.f - wx) : 0.f;
        const float vx1 = (xi + 1 >= 0 && xi + 1 < W) ? wx         : 0.f;
        const float vy0 = (yi >= 0 && yi < W)         ? (1.f - wy) : 0.f;
        const float vy1 = (yi + 1 >= 0 && yi + 1 < W) ? wy         : 0.f;

        // byte offsets into the image's v16 (incl. head channel base h*32ch*2B)
        const int hb  = h * 64;
        const int b00 = (start + y0 * W + x0) * 512 + hb;
        const int b01 = (start + y0 * W + x1) * 512 + hb;
        const int b10 = (start + y1 * W + x0) * 512 + hb;
        const int b11 = (start + y1 * W + x1) * 512 + hb;

        sW[wv][h * 17 + j0 + pp] = make_float4(wgt * vy0 * vx0, wgt * vy0 * vx1,
                                               wgt * vy1 * vx0, wgt * vy1 * vx1);
        sI[wv][h * 17 + j0 + pp] = make_int4(b00, b01, b10, b11);
    }
    __syncthreads();

    const char* vn = reinterpret_cast<const char*>(v16 + (size_t)n * LQ * 256);
    const int koff = k * 8;
    float4 acc = make_float4(0.f, 0.f, 0.f, 0.f);

#pragma unroll
    for (int j = 0; j < 16; ++j) {
        const float4 w = sW[wv][h * 17 + j];
        const int4   I = sI[wv][h * 17 + j];
        const ushort4 p00 = *reinterpret_cast<const ushort4*>(vn + I.x + koff);
        const ushort4 p01 = *reinterpret_cast<const ushort4*>(vn + I.y + koff);
        const ushort4 p10 = *reinterpret_cast<const ushort4*>(vn + I.z + koff);
        const ushort4 p11 = *reinterpret_cast<const ushort4*>(vn + I.w + koff);
        acc.x += w.x * b2f(p00.x) + w.y * b2f(p01.x) + w.z * b2f(p10.x) + w.w * b2f(p11.x);
        acc.y += w.x * b2f(p00.y) + w.y * b2f(p01.y) + w.z * b2f(p10.y) + w.w * b2f(p11.y);
        acc.z += w.x * b2f(p00.z) + w.y * b2f(p01.z) + w.z * b2f(p10.z) + w.w * b2f(p11.z);
        acc.w += w.x * b2f(p00.w) + w.y * b2f(p01.w) + w.z * b2f(p10.w) + w.w * b2f(p11.w);
    }

    ushort4 st;
    st.x = f2b(acc.x); st.y = f2b(acc.y); st.z = f2b(acc.z); st.w = f2b(acc.w);
    // lane (h,k) owns channels h*32+4k..+3  ->  ushort4 index row*64 + lane
    reinterpret_cast<ushort4*>(pre16)[(size_t)row * 64 + lane] = st;
}

// ---------------------------------------------------------------------------
extern "C" void kernel_launch(void* const* d_in, const int* in_sizes, int n_in,
                              void* d_out, int out_size, void* d_ws, size_t ws_size,
                              hipStream_t stream)
{
    const float* query   = (const float*)d_in[0];
    const float* refpts  = (const float*)d_in[1];
    const float* W_value = (const float*)d_in[4];
    const float* b_value = (const float*)d_in[5];
    const float* W_off   = (const float*)d_in[6];
    const float* b_off   = (const float*)d_in[7];
    const float* W_attn  = (const float*)d_in[8];
    const float* b_attn  = (const float*)d_in[9];
    const float* W_out   = (const float*)d_in[10];
    const float* b_out   = (const float*)d_in[11];
    float* out = (float*)d_out;

    // Workspace (bf16): v16 | off16 | attn16 | pre16 | WvT | WoaT | WoT
    unsigned short* ws_v16   = (unsigned short*)d_ws;
    unsigned short* ws_off16 = ws_v16   + (size_t)MROWS * 256;
    unsigned short* ws_at16  = ws_off16 + (size_t)MROWS * 256;
    unsigned short* ws_pre16 = ws_at16  + (size_t)MROWS * 128;
    unsigned short* ws_wvT   = ws_pre16 + (size_t)MROWS * 256;
    unsigned short* ws_woaT  = ws_wvT   + 65536;
    unsigned short* ws_woT   = ws_woaT  + 98304;

    prep_weights<<<dim3(896), 256, 0, stream>>>(
        W_value, W_off, W_attn, W_out, ws_wvT, ws_woaT, ws_woT);

    // v16 = bf16(query @ W_value + b_value)
    gemm_mfma<true, true><<<dim3(2, 340), 256, 0, stream>>>(
        query, ws_wvT, b_value, b_value, ws_v16, ws_v16, 256, 256, 1 << 30);

    // off16 / attn16 = bf16(v @ [W_off | W_attn] + bias)
    gemm_mfma<false, true><<<dim3(3, 340), 256, 0, stream>>>(
        ws_v16, ws_woaT, b_off, b_attn, ws_off16, ws_at16, 256, 128, 256);

    // fused softmax + bilinear sampling -> pre16
    sample_kernel<<<dim3(MROWS / 4), 256, 0, stream>>>(
        ws_v16, ws_off16, ws_at16, refpts, ws_pre16);

    // out = pre @ W_out + b_out  (fp32)
    gemm_mfma<false, false><<<dim3(2, 340), 256, 0, stream>>>(
        ws_pre16, ws_woT, b_out, b_out, out, out, 256, 256, 1 << 30);
}